// Round 11
// baseline (528.110 us; speedup 1.0000x reference)
//
#include <hip/hip_runtime.h>
#include <hip/hip_bf16.h>
#include <math.h>

#define D 128
#define G_GRAPHS 512
#define C_CLASSES 10
#define BN_EPS 1e-5f
#define NBUCK_MAX 512     // supports N <= 131072 (bucket = node >> 8)
#define EDGE_CHUNK 4096
#define EPT 16            // EDGE_CHUNK / 256

typedef unsigned short u16;
typedef unsigned int u32;
typedef unsigned short ushort4_t __attribute__((ext_vector_type(4)));
typedef unsigned short ushort8_t __attribute__((ext_vector_type(8)));
typedef __bf16 bf16x8 __attribute__((ext_vector_type(8)));
typedef float floatx4 __attribute__((ext_vector_type(4)));
union B8 { ushort8_t u; bf16x8 b; };

__device__ __forceinline__ float bf_lo(u32 v) { return __uint_as_float(v << 16); }
__device__ __forceinline__ float bf_hi(u32 v) { return __uint_as_float(v & 0xffff0000u); }
__device__ __forceinline__ u16 f2bf(float f) {
    union { float f; u32 u; } x; x.f = f;
    u32 r = x.u + 0x7fff + ((x.u >> 16) & 1);  // RN-even
    return (u16)(r >> 16);
}
__device__ __forceinline__ u32 pack2bf(float a, float b) {
    return (u32)f2bf(a) | ((u32)f2bf(b) << 16);
}

// ============ CSR build: two-level counting sort ============

__global__ __launch_bounds__(256) void bucket_hist_kernel(
    const int* __restrict__ dst, int* __restrict__ bucketCnt, int E, int nbuck)
{
    __shared__ int h[NBUCK_MAX];
    int tid = threadIdx.x;
    for (int i = tid; i < NBUCK_MAX; i += 256) h[i] = 0;
    __syncthreads();
    for (int i = blockIdx.x * 256 + tid; i < E; i += gridDim.x * 256)
        atomicAdd(&h[dst[i] >> 8], 1);
    __syncthreads();
    for (int i = tid; i < nbuck; i += 256)
        if (h[i]) atomicAdd(&bucketCnt[i], h[i]);
}

__global__ void scan_buckets_kernel(
    const int* __restrict__ bucketCnt, int* __restrict__ bucketBase,
    int* __restrict__ bucketCursor, int* __restrict__ rowPtr, int nbuck, int N, int E)
{
    __shared__ int buf[2][512];
    int tid = threadIdx.x;
    int v = (tid < nbuck) ? bucketCnt[tid] : 0;
    buf[0][tid] = v;
    __syncthreads();
    int cur = 0;
    for (int off = 1; off < 512; off <<= 1) {
        buf[1 - cur][tid] = buf[cur][tid] + ((tid >= off) ? buf[cur][tid - off] : 0);
        cur ^= 1;
        __syncthreads();
    }
    if (tid < nbuck) {
        int b = buf[cur][tid] - v;  // exclusive
        bucketBase[tid] = b;
        bucketCursor[tid] = b;
    }
    if (tid == 0) { bucketBase[nbuck] = E; rowPtr[N] = E; }
}

// pairs packed: (src << 8) | (dst & 255)   [src < 2^17, fits 25 bits]
__global__ __launch_bounds__(256) void scatter_pairs_kernel(
    const int* __restrict__ src, const int* __restrict__ dst,
    int* __restrict__ bucketCursor, u32* __restrict__ pairs, int E)
{
    __shared__ int h[NBUCK_MAX];
    __shared__ int base[NBUCK_MAX];
    int tid = threadIdx.x;
    int e0 = blockIdx.x * EDGE_CHUNK;
    for (int i = tid; i < NBUCK_MAX; i += 256) h[i] = 0;
    __syncthreads();
    int s[EPT], d[EPT], r[EPT];
#pragma unroll
    for (int j = 0; j < EPT; ++j) {
        int i = e0 + j * 256 + tid;
        if (i < E) {
            s[j] = src[i];
            d[j] = dst[i];
            r[j] = atomicAdd(&h[d[j] >> 8], 1);
        } else {
            d[j] = -1;
        }
    }
    __syncthreads();
    for (int i = tid; i < NBUCK_MAX; i += 256)
        if (h[i]) base[i] = atomicAdd(&bucketCursor[i], h[i]);
    __syncthreads();
#pragma unroll
    for (int j = 0; j < EPT; ++j) {
        if (d[j] >= 0) {
            int b = d[j] >> 8;
            pairs[base[b] + r[j]] = ((u32)s[j] << 8) | (u32)(d[j] & 255);
        }
    }
}

__global__ __launch_bounds__(256) void bucket_sort_kernel(
    const u32* __restrict__ pairs, const int* __restrict__ bucketBase,
    int* __restrict__ colIdx, int* __restrict__ rowPtr, float* __restrict__ dinv, int N)
{
    __shared__ int h[256];
    __shared__ int cur[256];
    __shared__ int sbuf[2][256];
    int tid = threadIdx.x;
    int b = blockIdx.x;
    int s = bucketBase[b], e = bucketBase[b + 1];
    h[tid] = 0;
    __syncthreads();
    for (int i = s + tid; i < e; i += 256)
        atomicAdd(&h[pairs[i] & 255], 1);
    __syncthreads();
    int cnt = h[tid];
    sbuf[0][tid] = cnt;
    __syncthreads();
    int c = 0;
    for (int off = 1; off < 256; off <<= 1) {
        sbuf[1 - c][tid] = sbuf[c][tid] + ((tid >= off) ? sbuf[c][tid - off] : 0);
        c ^= 1;
        __syncthreads();
    }
    int excl = sbuf[c][tid] - cnt;
    int v = b * 256 + tid;
    if (v < N) {
        rowPtr[v] = s + excl;
        dinv[v] = rsqrtf((float)(cnt + 1));  // +1 self loop
    }
    cur[tid] = s + excl;
    __syncthreads();
    for (int i = s + tid; i < e; i += 256) {
        u32 p = pairs[i];
        int pos = atomicAdd(&cur[p & 255], 1);
        colIdx[pos] = (int)(p >> 8);
    }
}

// ---------------- graph segments: boundary detection on sorted batch ----------------
__global__ __launch_bounds__(256) void graph_bounds_kernel(
    const int* __restrict__ batch, int* __restrict__ gstart, int N)
{
    int i = blockIdx.x * 256 + threadIdx.x;
    if (i >= N) return;
    int b = batch[i];
    int prev = (i == 0) ? -1 : batch[i - 1];
    if (b != prev) {
        for (int g = prev + 1; g <= b; ++g) gstart[g] = i;  // covers empty graphs
    }
    if (i == N - 1) {
        for (int g = b + 1; g <= G_GRAPHS; ++g) gstart[g] = N;
    }
}

// ---------------- W pre-transpose+convert: Wt[n][k] bf16 ----------------
__global__ __launch_bounds__(256) void wconv_kernel(
    const float4* __restrict__ w1, const float4* __restrict__ w2,
    const float4* __restrict__ w3, u16* __restrict__ wtAll)
{
    const float4* W = (blockIdx.x == 0) ? w1 : (blockIdx.x == 1) ? w2 : w3;
    u16* Wt = wtAll + (size_t)blockIdx.x * D * D;
    int tid = threadIdx.x;
#pragma unroll
    for (int i = 0; i < 16; ++i) {
        int idx = tid + i * 256;        // = k*32 + c4
        int k = idx >> 5, c4 = idx & 31;
        float4 v = W[idx];
        Wt[(4 * c4 + 0) * D + k] = f2bf(v.x);
        Wt[(4 * c4 + 1) * D + k] = f2bf(v.y);
        Wt[(4 * c4 + 2) * D + k] = f2bf(v.z);
        Wt[(4 * c4 + 3) * D + k] = f2bf(v.w);
    }
}

// ---------------- MFMA GEMM core (A=W frag, B=X frag; 8B stores) ----------------
#define XS_STRIDE 136

__device__ __forceinline__ void gemm_core_and_store(
    const u16* Xs, const u16* Ws, u16* __restrict__ Y, int row0, int nrows, int tid)
{
    int wid = tid >> 6, lane = tid & 63;
    int m = lane & 15, quad = lane >> 4;
    int xrow = wid * 16 + m;

    floatx4 acc[8] = {};
#pragma unroll
    for (int ks = 0; ks < 4; ++ks) {
        int kk = ks * 32 + quad * 8;
        B8 a;
        a.u = *(const ushort8_t*)&Xs[xrow * XS_STRIDE + kk];
#pragma unroll
        for (int t = 0; t < 8; ++t) {
            B8 b;
            b.u = *(const ushort8_t*)&Ws[(t * 16 + m) * XS_STRIDE + kk];
            acc[t] = __builtin_amdgcn_mfma_f32_16x16x32_bf16(b.b, a.b, acc[t], 0, 0, 0);
        }
    }
    int grow = row0 + xrow;
    if (grow < nrows) {
#pragma unroll
        for (int t = 0; t < 8; ++t) {
            ushort4_t o;
            o.x = f2bf(acc[t][0]); o.y = f2bf(acc[t][1]);
            o.z = f2bf(acc[t][2]); o.w = f2bf(acc[t][3]);
            *(ushort4_t*)&Y[(size_t)grow * D + t * 16 + quad * 4] = o;
        }
    }
}

__device__ __forceinline__ void stage_w(const u16* __restrict__ Wt, u16* Ws, int tid) {
    const ushort8_t* Wv = (const ushort8_t*)Wt;
#pragma unroll
    for (int i = 0; i < 8; ++i) {
        int idx = tid + i * 256;        // = n*16 + c8
        int n = idx >> 4, c8 = idx & 15;
        *(ushort8_t*)&Ws[n * XS_STRIDE + c8 * 8] = Wv[idx];
    }
}

// layer 1: X fp32, persistent tiles
__global__ __launch_bounds__(256) void gemm_mfma_f32in_kernel(
    const float4* __restrict__ X, const u16* __restrict__ Wt,
    u16* __restrict__ Y, int nrows, int ntiles)
{
    __shared__ __align__(16) u16 Xs[64 * XS_STRIDE];
    __shared__ __align__(16) u16 Ws[128 * XS_STRIDE];
    int tid = threadIdx.x;
    stage_w(Wt, Ws, tid);
    for (int t = blockIdx.x; t < ntiles; t += gridDim.x) {
        int row0 = t * 64;
        __syncthreads();   // Ws ready / prev tile's reads done
#pragma unroll
        for (int i = 0; i < 8; ++i) {
            int idx = tid + i * 256;        // = r*32 + c4
            int r = idx >> 5, c4 = idx & 31;
            int gr = row0 + r;
            float4 v = make_float4(0.f, 0.f, 0.f, 0.f);
            if (gr < nrows) v = X[(size_t)gr * 32 + c4];
            ushort4_t o;
            o.x = f2bf(v.x); o.y = f2bf(v.y); o.z = f2bf(v.z); o.w = f2bf(v.w);
            *(ushort4_t*)&Xs[r * XS_STRIDE + c4 * 4] = o;
        }
        __syncthreads();
        gemm_core_and_store(Xs, Ws, Y, row0, nrows, tid);
    }
}

// layers 2/3: X bf16, optional fused bn(from raw stats)+relu on input, persistent
__global__ __launch_bounds__(256) void gemm_mfma_bf16in_kernel(
    const uint4* __restrict__ X, const u16* __restrict__ Wt,
    const float* __restrict__ gsum, const float* __restrict__ gsq,
    const float* __restrict__ gamma, const float* __restrict__ beta, float invN,
    u16* __restrict__ Y, int nrows, int ntiles)
{
    __shared__ __align__(16) u16 Xs[64 * XS_STRIDE];
    __shared__ __align__(16) u16 Ws[128 * XS_STRIDE];
    __shared__ float scs[D], shs[D];
    int tid = threadIdx.x;
    bool fuse = (gsum != nullptr);
    stage_w(Wt, Ws, tid);
    if (fuse && tid < D) {
        float mu = gsum[tid] * invN;
        float var = gsq[tid] * invN - mu * mu;
        float sc = gamma[tid] * rsqrtf(var + BN_EPS);
        scs[tid] = sc;
        shs[tid] = beta[tid] - mu * sc;
    }
    for (int t = blockIdx.x; t < ntiles; t += gridDim.x) {
        int row0 = t * 64;
        __syncthreads();   // Ws/scs ready / prev tile's reads done
#pragma unroll
        for (int i = 0; i < 4; ++i) {
            int idx = tid + i * 256;        // = r*16 + c8
            int r = idx >> 4, c8 = idx & 15;
            int gr = row0 + r;
            uint4 v = make_uint4(0, 0, 0, 0);
            if (gr < nrows) v = X[(size_t)gr * 16 + c8];
            if (fuse) {
                int k = c8 * 8;
                v.x = pack2bf(fmaxf(bf_lo(v.x) * scs[k]     + shs[k],     0.f),
                              fmaxf(bf_hi(v.x) * scs[k + 1] + shs[k + 1], 0.f));
                v.y = pack2bf(fmaxf(bf_lo(v.y) * scs[k + 2] + shs[k + 2], 0.f),
                              fmaxf(bf_hi(v.y) * scs[k + 3] + shs[k + 3], 0.f));
                v.z = pack2bf(fmaxf(bf_lo(v.z) * scs[k + 4] + shs[k + 4], 0.f),
                              fmaxf(bf_hi(v.z) * scs[k + 5] + shs[k + 5], 0.f));
                v.w = pack2bf(fmaxf(bf_lo(v.w) * scs[k + 6] + shs[k + 6], 0.f),
                              fmaxf(bf_hi(v.w) * scs[k + 7] + shs[k + 7], 0.f));
            }
            *(uint4*)&Xs[r * XS_STRIDE + c8 * 8] = v;
        }
        __syncthreads();
        gemm_core_and_store(Xs, Ws, Y, row0, nrows, tid);
    }
}

// ---------------- aggregation v6: v5 gather + persistent grid + fused BN stats ----------------
#define ACC8(tw, duu)                                              \
    acc[0] += (duu) * bf_lo((tw).x); acc[1] += (duu) * bf_hi((tw).x); \
    acc[2] += (duu) * bf_lo((tw).y); acc[3] += (duu) * bf_hi((tw).y); \
    acc[4] += (duu) * bf_lo((tw).z); acc[5] += (duu) * bf_hi((tw).z); \
    acc[6] += (duu) * bf_lo((tw).w); acc[7] += (duu) * bf_hi((tw).w);

__global__ __launch_bounds__(256) void aggregate_kernel(
    const uint4* __restrict__ T, const int* __restrict__ colIdx,
    const int* __restrict__ rowPtr, const float* __restrict__ dinv,
    const float* __restrict__ bias, uint4* __restrict__ outH, int n, int ntiles,
    float* __restrict__ gsum, float* __restrict__ gsq)
{
    int tid = threadIdx.x;
    int wid = tid >> 6;
    int lane = tid & 63;
    int fg = lane & 15;     // 16B slice within the 256B row
    int eg = lane >> 4;     // which of the wave's 4 rows
    bool doStats = (gsum != nullptr);
    float ssum[8] = {}, ssq[8] = {};

    const float4* bp = (const float4*)bias;
    float4 b0 = bp[fg * 2], b1 = bp[fg * 2 + 1];

    for (int tile = blockIdx.x; tile < ntiles; tile += gridDim.x) {
        int row = (tile * 4 + wid) * 4 + eg;
        bool active = row < n;

        float dr = 0.f;
        int s = 0, m = 0;
        float acc[8] = {};
        if (active) {
            dr = dinv[row];
            s = rowPtr[row];
            m = rowPtr[row + 1] - s;
            uint4 sv = T[(size_t)row * 16 + fg];   // self loop
            acc[0] = dr * bf_lo(sv.x); acc[1] = dr * bf_hi(sv.x);
            acc[2] = dr * bf_lo(sv.y); acc[3] = dr * bf_hi(sv.y);
            acc[4] = dr * bf_lo(sv.z); acc[5] = dr * bf_hi(sv.z);
            acc[6] = dr * bf_lo(sv.w); acc[7] = dr * bf_hi(sv.w);
        }

        // m is uniform within each 16-lane group
        for (int c0 = 0; c0 < m; c0 += 16) {
            int mm = m - c0;
            if (mm > 16) mm = 16;
            int u = row;        // pad slots: own (hot) row, weight 0
            float du = 0.f;
            if (fg < mm) {
                u = colIdx[s + c0 + fg];
                du = dinv[u];
            }
            int nb = (mm + 3) >> 2;
            for (int b = 0; b < nb; ++b) {
                int base = (eg << 4) + (b << 2);   // sources within own group
                int u0 = __shfl(u, base);     float d0 = __shfl(du, base);
                int u1 = __shfl(u, base + 1); float d1 = __shfl(du, base + 1);
                int u2 = __shfl(u, base + 2); float d2 = __shfl(du, base + 2);
                int u3 = __shfl(u, base + 3); float d3 = __shfl(du, base + 3);
                uint4 t0 = T[(size_t)u0 * 16 + fg];
                uint4 t1 = T[(size_t)u1 * 16 + fg];
                uint4 t2 = T[(size_t)u2 * 16 + fg];
                uint4 t3 = T[(size_t)u3 * 16 + fg];
                ACC8(t0, d0); ACC8(t1, d1); ACC8(t2, d2); ACC8(t3, d3);
            }
        }

        if (active) {
            float hv[8];
            hv[0] = fmaxf(dr * acc[0] + b0.x, 0.f);
            hv[1] = fmaxf(dr * acc[1] + b0.y, 0.f);
            hv[2] = fmaxf(dr * acc[2] + b0.z, 0.f);
            hv[3] = fmaxf(dr * acc[3] + b0.w, 0.f);
            hv[4] = fmaxf(dr * acc[4] + b1.x, 0.f);
            hv[5] = fmaxf(dr * acc[5] + b1.y, 0.f);
            hv[6] = fmaxf(dr * acc[6] + b1.z, 0.f);
            hv[7] = fmaxf(dr * acc[7] + b1.w, 0.f);
            uint4 o;
            o.x = pack2bf(hv[0], hv[1]);
            o.y = pack2bf(hv[2], hv[3]);
            o.z = pack2bf(hv[4], hv[5]);
            o.w = pack2bf(hv[6], hv[7]);
            outH[(size_t)row * 16 + fg] = o;
            if (doStats) {
#pragma unroll
                for (int j = 0; j < 8; ++j) {
                    ssum[j] += hv[j];
                    ssq[j] += hv[j] * hv[j];
                }
            }
        }
    }

    if (doStats) {
        __shared__ float lsum[D], lsq[D];
        if (tid < D) { lsum[tid] = 0.f; lsq[tid] = 0.f; }
        __syncthreads();
#pragma unroll
        for (int j = 0; j < 8; ++j) {
            atomicAdd(&lsum[fg * 8 + j], ssum[j]);
            atomicAdd(&lsq[fg * 8 + j], ssq[j]);
        }
        __syncthreads();
        if (tid < D) {
            atomicAdd(&gsum[tid], lsum[tid]);
            atomicAdd(&gsq[tid], lsq[tid]);
        }
    }
}

// ---------------- pool (bn2 from raw stats + relu) + classify + log_softmax ----------------
__global__ __launch_bounds__(256) void pool_classify_kernel(
    const u32* __restrict__ H, const float* __restrict__ gsum, const float* __restrict__ gsq,
    const float* __restrict__ gamma, const float* __restrict__ beta, float invN,
    const int* __restrict__ gstart, const float* __restrict__ fcw,
    const float* __restrict__ fcb, float* __restrict__ out)
{
    int g = blockIdx.x;
    int tid = threadIdx.x;
    int c = tid & 63, q = tid >> 6;
    float muA = gsum[2 * c] * invN, muB = gsum[2 * c + 1] * invN;
    float vA = gsq[2 * c] * invN - muA * muA, vB = gsq[2 * c + 1] * invN - muB * muB;
    float scA = gamma[2 * c] * rsqrtf(vA + BN_EPS), scB = gamma[2 * c + 1] * rsqrtf(vB + BN_EPS);
    float shA = beta[2 * c] - muA * scA, shB = beta[2 * c + 1] - muB * scB;

    int s = gstart[g], cnt = gstart[g + 1] - s;
    float aA = 0.f, aB = 0.f;
    for (int i = q; i < cnt; i += 4) {
        u32 v = H[(size_t)(s + i) * 64 + c];
        aA += fmaxf(bf_lo(v) * scA + shA, 0.f);
        aB += fmaxf(bf_hi(v) * scB + shB, 0.f);
    }
    __shared__ float sA[256], sB[256];
    __shared__ float prow[D];
    __shared__ float lg[C_CLASSES];
    sA[tid] = aA; sB[tid] = aB;
    __syncthreads();
    if (tid < 64) {
        float tA = sA[tid] + sA[tid + 64] + sA[tid + 128] + sA[tid + 192];
        float tB = sB[tid] + sB[tid + 64] + sB[tid + 128] + sB[tid + 192];
        float inv = 1.f / (float)(cnt > 1 ? cnt : 1);
        prow[2 * tid] = tA * inv;
        prow[2 * tid + 1] = tB * inv;
    }
    __syncthreads();
    if (tid < C_CLASSES) {
        float sum = fcb[tid];
        for (int d = 0; d < D; ++d) sum += prow[d] * fcw[d * C_CLASSES + tid];
        lg[tid] = sum;
    }
    __syncthreads();
    if (tid == 0) {
        float mx = -1e30f;
        for (int k = 0; k < C_CLASSES; ++k) mx = fmaxf(mx, lg[k]);
        float se = 0.f;
        for (int k = 0; k < C_CLASSES; ++k) se += expf(lg[k] - mx);
        float lse = mx + logf(se);
        for (int k = 0; k < C_CLASSES; ++k) out[(size_t)g * C_CLASSES + k] = lg[k] - lse;
    }
}

extern "C" void kernel_launch(void* const* d_in, const int* in_sizes, int n_in,
                              void* d_out, int out_size, void* d_ws, size_t ws_size,
                              hipStream_t stream) {
    const float* x   = (const float*)d_in[0];
    const int* ei    = (const int*)d_in[1];
    const int* batch = (const int*)d_in[2];
    const float* w1  = (const float*)d_in[3];
    const float* b1  = (const float*)d_in[4];
    const float* w2  = (const float*)d_in[5];
    const float* b2  = (const float*)d_in[6];
    const float* w3  = (const float*)d_in[7];
    const float* b3  = (const float*)d_in[8];
    const float* g1  = (const float*)d_in[9];
    const float* be1 = (const float*)d_in[10];
    const float* g2  = (const float*)d_in[11];
    const float* be2 = (const float*)d_in[12];
    const float* fcw = (const float*)d_in[13];
    const float* fcb = (const float*)d_in[14];

    const int N = in_sizes[0] / D;
    const int E = in_sizes[1] / 2;
    const int* src = ei;
    const int* dst = ei + E;
    const int nbuck = (N + 255) >> 8;
    const float invN = 1.f / (float)N;

    char* p = (char*)d_ws;
    auto alloc = [&](size_t bytes) -> void* {
        void* r = (void*)p;
        p += (bytes + 255) & ~(size_t)255;
        return r;
    };
    // bucketCnt + statsacc adjacent -> one memset
    int*   bucketCnt    = (int*)alloc(NBUCK_MAX * 4);
    float* statsacc     = (float*)alloc(4 * D * 4);
    float* gsum1 = statsacc, *gsq1 = statsacc + D, *gsum2 = statsacc + 2 * D, *gsq2 = statsacc + 3 * D;
    float* dinv     = (float*)alloc((size_t)N * 4);
    int*   rowPtr   = (int*)alloc((size_t)(N + 1) * 4);
    int*   colIdx   = (int*)alloc((size_t)E * 4);
    u32*   pairs    = (u32*)alloc((size_t)E * 4);
    int*   bucketBase   = (int*)alloc((NBUCK_MAX + 1) * 4);
    int*   bucketCursor = (int*)alloc(NBUCK_MAX * 4);
    int*   gstart  = (int*)alloc((G_GRAPHS + 1) * 4);
    u16*   wtAll   = (u16*)alloc((size_t)3 * D * D * 2);   // bf16 W^T x3
    u16*   tmp     = (u16*)alloc((size_t)N * D * 2);       // bf16 gemm out
    u16*   hbuf    = (u16*)alloc((size_t)N * D * 2);       // bf16 agg out

    hipMemsetAsync(bucketCnt, 0, NBUCK_MAX * 4 + 4 * D * 4, stream);

    // ---- graph structure ----
    bucket_hist_kernel<<<512, 256, 0, stream>>>(dst, bucketCnt, E, nbuck);
    scan_buckets_kernel<<<1, 512, 0, stream>>>(bucketCnt, bucketBase, bucketCursor, rowPtr, nbuck, N, E);
    scatter_pairs_kernel<<<(E + EDGE_CHUNK - 1) / EDGE_CHUNK, 256, 0, stream>>>(src, dst, bucketCursor, pairs, E);
    bucket_sort_kernel<<<nbuck, 256, 0, stream>>>(pairs, bucketBase, colIdx, rowPtr, dinv, N);
    graph_bounds_kernel<<<(N + 255) / 256, 256, 0, stream>>>(batch, gstart, N);
    wconv_kernel<<<3, 256, 0, stream>>>((const float4*)w1, (const float4*)w2, (const float4*)w3, wtAll);

    const int NT = (N + 63) / 64;            // gemm tiles
    const int GB = (NT + 1) / 2;             // exactly 2 tiles/block (even split)
    const int AT = (N + 15) / 16;            // aggregate tiles (16 rows each)
    const int AGB = (AT + 3) / 4;            // 4 tiles/block (whole grid ~resident)

    gemm_mfma_f32in_kernel<<<GB, 256, 0, stream>>>((const float4*)x, wtAll, tmp, N, NT);
    aggregate_kernel<<<AGB, 256, 0, stream>>>((const uint4*)tmp, colIdx, rowPtr, dinv, b1,
        (uint4*)hbuf, N, AT, nullptr, nullptr);
    gemm_mfma_bf16in_kernel<<<GB, 256, 0, stream>>>((const uint4*)hbuf, wtAll + D * D,
        nullptr, nullptr, nullptr, nullptr, 0.f, tmp, N, NT);
    aggregate_kernel<<<AGB, 256, 0, stream>>>((const uint4*)tmp, colIdx, rowPtr, dinv, b2,
        (uint4*)hbuf, N, AT, gsum1, gsq1);
    gemm_mfma_bf16in_kernel<<<GB, 256, 0, stream>>>((const uint4*)hbuf, wtAll + 2 * D * D,
        gsum1, gsq1, g1, be1, invN, tmp, N, NT);
    aggregate_kernel<<<AGB, 256, 0, stream>>>((const uint4*)tmp, colIdx, rowPtr, dinv, b3,
        (uint4*)hbuf, N, AT, gsum2, gsq2);
    pool_classify_kernel<<<G_GRAPHS, 256, 0, stream>>>((const u32*)hbuf, gsum2, gsq2, g2, be2, invN,
        gstart, fcw, fcb, (float*)d_out);
}

// Round 12
// 514.859 us; speedup vs baseline: 1.0257x; 1.0257x over previous
//
#include <hip/hip_runtime.h>
#include <hip/hip_bf16.h>
#include <math.h>

#define D 128
#define G_GRAPHS 512
#define C_CLASSES 10
#define BN_EPS 1e-5f
#define NBUCK_MAX 512     // supports N <= 131072 (bucket = node >> 8)
#define EDGE_CHUNK 4096
#define EPT 16            // EDGE_CHUNK / 256

typedef unsigned short u16;
typedef unsigned int u32;
typedef unsigned short ushort4_t __attribute__((ext_vector_type(4)));
typedef unsigned short ushort8_t __attribute__((ext_vector_type(8)));
typedef __bf16 bf16x8 __attribute__((ext_vector_type(8)));
typedef float floatx4 __attribute__((ext_vector_type(4)));
union B8 { ushort8_t u; bf16x8 b; };

__device__ __forceinline__ float bf_lo(u32 v) { return __uint_as_float(v << 16); }
__device__ __forceinline__ float bf_hi(u32 v) { return __uint_as_float(v & 0xffff0000u); }
__device__ __forceinline__ u16 f2bf(float f) {
    union { float f; u32 u; } x; x.f = f;
    u32 r = x.u + 0x7fff + ((x.u >> 16) & 1);  // RN-even
    return (u16)(r >> 16);
}
__device__ __forceinline__ u32 pack2bf(float a, float b) {
    return (u32)f2bf(a) | ((u32)f2bf(b) << 16);
}

// ============ CSR build: two-level counting sort ============

__global__ __launch_bounds__(256) void bucket_hist_kernel(
    const int* __restrict__ dst, int* __restrict__ bucketCnt, int E, int nbuck)
{
    __shared__ int h[NBUCK_MAX];
    int tid = threadIdx.x;
    for (int i = tid; i < NBUCK_MAX; i += 256) h[i] = 0;
    __syncthreads();
    for (int i = blockIdx.x * 256 + tid; i < E; i += gridDim.x * 256)
        atomicAdd(&h[dst[i] >> 8], 1);
    __syncthreads();
    for (int i = tid; i < nbuck; i += 256)
        if (h[i]) atomicAdd(&bucketCnt[i], h[i]);
}

__global__ void scan_buckets_kernel(
    const int* __restrict__ bucketCnt, int* __restrict__ bucketBase,
    int* __restrict__ bucketCursor, int* __restrict__ rowPtr, int nbuck, int N, int E)
{
    __shared__ int buf[2][512];
    int tid = threadIdx.x;
    int v = (tid < nbuck) ? bucketCnt[tid] : 0;
    buf[0][tid] = v;
    __syncthreads();
    int cur = 0;
    for (int off = 1; off < 512; off <<= 1) {
        buf[1 - cur][tid] = buf[cur][tid] + ((tid >= off) ? buf[cur][tid - off] : 0);
        cur ^= 1;
        __syncthreads();
    }
    if (tid < nbuck) {
        int b = buf[cur][tid] - v;  // exclusive
        bucketBase[tid] = b;
        bucketCursor[tid] = b;
    }
    if (tid == 0) { bucketBase[nbuck] = E; rowPtr[N] = E; }
}

// pairs packed: (src << 8) | (dst & 255)   [src < 2^17, fits 25 bits]
__global__ __launch_bounds__(256) void scatter_pairs_kernel(
    const int* __restrict__ src, const int* __restrict__ dst,
    int* __restrict__ bucketCursor, u32* __restrict__ pairs, int E)
{
    __shared__ int h[NBUCK_MAX];
    __shared__ int base[NBUCK_MAX];
    int tid = threadIdx.x;
    int e0 = blockIdx.x * EDGE_CHUNK;
    for (int i = tid; i < NBUCK_MAX; i += 256) h[i] = 0;
    __syncthreads();
    int s[EPT], d[EPT], r[EPT];
#pragma unroll
    for (int j = 0; j < EPT; ++j) {
        int i = e0 + j * 256 + tid;
        if (i < E) {
            s[j] = src[i];
            d[j] = dst[i];
            r[j] = atomicAdd(&h[d[j] >> 8], 1);
        } else {
            d[j] = -1;
        }
    }
    __syncthreads();
    for (int i = tid; i < NBUCK_MAX; i += 256)
        if (h[i]) base[i] = atomicAdd(&bucketCursor[i], h[i]);
    __syncthreads();
#pragma unroll
    for (int j = 0; j < EPT; ++j) {
        if (d[j] >= 0) {
            int b = d[j] >> 8;
            pairs[base[b] + r[j]] = ((u32)s[j] << 8) | (u32)(d[j] & 255);
        }
    }
}

__global__ __launch_bounds__(256) void bucket_sort_kernel(
    const u32* __restrict__ pairs, const int* __restrict__ bucketBase,
    int* __restrict__ colIdx, int* __restrict__ rowPtr, float* __restrict__ dinv, int N)
{
    __shared__ int h[256];
    __shared__ int cur[256];
    __shared__ int sbuf[2][256];
    int tid = threadIdx.x;
    int b = blockIdx.x;
    int s = bucketBase[b], e = bucketBase[b + 1];
    h[tid] = 0;
    __syncthreads();
    for (int i = s + tid; i < e; i += 256)
        atomicAdd(&h[pairs[i] & 255], 1);
    __syncthreads();
    int cnt = h[tid];
    sbuf[0][tid] = cnt;
    __syncthreads();
    int c = 0;
    for (int off = 1; off < 256; off <<= 1) {
        sbuf[1 - c][tid] = sbuf[c][tid] + ((tid >= off) ? sbuf[c][tid - off] : 0);
        c ^= 1;
        __syncthreads();
    }
    int excl = sbuf[c][tid] - cnt;
    int v = b * 256 + tid;
    if (v < N) {
        rowPtr[v] = s + excl;
        dinv[v] = rsqrtf((float)(cnt + 1));  // +1 self loop
    }
    cur[tid] = s + excl;
    __syncthreads();
    for (int i = s + tid; i < e; i += 256) {
        u32 p = pairs[i];
        int pos = atomicAdd(&cur[p & 255], 1);
        colIdx[pos] = (int)(p >> 8);
    }
}

// ---------------- graph segments: boundary detection on sorted batch ----------------
__global__ __launch_bounds__(256) void graph_bounds_kernel(
    const int* __restrict__ batch, int* __restrict__ gstart, int N)
{
    int i = blockIdx.x * 256 + threadIdx.x;
    if (i >= N) return;
    int b = batch[i];
    int prev = (i == 0) ? -1 : batch[i - 1];
    if (b != prev) {
        for (int g = prev + 1; g <= b; ++g) gstart[g] = i;  // covers empty graphs
    }
    if (i == N - 1) {
        for (int g = b + 1; g <= G_GRAPHS; ++g) gstart[g] = N;
    }
}

// ---------------- W pre-transpose+convert: Wt[n][k] bf16 ----------------
__global__ __launch_bounds__(256) void wconv_kernel(
    const float4* __restrict__ w1, const float4* __restrict__ w2,
    const float4* __restrict__ w3, u16* __restrict__ wtAll)
{
    const float4* W = (blockIdx.x == 0) ? w1 : (blockIdx.x == 1) ? w2 : w3;
    u16* Wt = wtAll + (size_t)blockIdx.x * D * D;
    int tid = threadIdx.x;
#pragma unroll
    for (int i = 0; i < 16; ++i) {
        int idx = tid + i * 256;        // = k*32 + c4
        int k = idx >> 5, c4 = idx & 31;
        float4 v = W[idx];
        Wt[(4 * c4 + 0) * D + k] = f2bf(v.x);
        Wt[(4 * c4 + 1) * D + k] = f2bf(v.y);
        Wt[(4 * c4 + 2) * D + k] = f2bf(v.z);
        Wt[(4 * c4 + 3) * D + k] = f2bf(v.w);
    }
}

// ---------------- MFMA GEMM core (A=W frag, B=X frag; 8B stores) ----------------
#define XS_STRIDE 136

__device__ __forceinline__ void gemm_core_and_store(
    const u16* Xs, const u16* Ws, u16* __restrict__ Y, int row0, int nrows, int tid)
{
    int wid = tid >> 6, lane = tid & 63;
    int m = lane & 15, quad = lane >> 4;
    int xrow = wid * 16 + m;

    floatx4 acc[8] = {};
#pragma unroll
    for (int ks = 0; ks < 4; ++ks) {
        int kk = ks * 32 + quad * 8;
        B8 a;
        a.u = *(const ushort8_t*)&Xs[xrow * XS_STRIDE + kk];
#pragma unroll
        for (int t = 0; t < 8; ++t) {
            B8 b;
            b.u = *(const ushort8_t*)&Ws[(t * 16 + m) * XS_STRIDE + kk];
            acc[t] = __builtin_amdgcn_mfma_f32_16x16x32_bf16(b.b, a.b, acc[t], 0, 0, 0);
        }
    }
    int grow = row0 + xrow;
    if (grow < nrows) {
#pragma unroll
        for (int t = 0; t < 8; ++t) {
            ushort4_t o;
            o.x = f2bf(acc[t][0]); o.y = f2bf(acc[t][1]);
            o.z = f2bf(acc[t][2]); o.w = f2bf(acc[t][3]);
            *(ushort4_t*)&Y[(size_t)grow * D + t * 16 + quad * 4] = o;
        }
    }
}

__device__ __forceinline__ void stage_w(const u16* __restrict__ Wt, u16* Ws, int tid) {
    const ushort8_t* Wv = (const ushort8_t*)Wt;
#pragma unroll
    for (int i = 0; i < 8; ++i) {
        int idx = tid + i * 256;        // = n*16 + c8
        int n = idx >> 4, c8 = idx & 15;
        *(ushort8_t*)&Ws[n * XS_STRIDE + c8 * 8] = Wv[idx];
    }
}

// layer 1: X fp32, persistent tiles
__global__ __launch_bounds__(256) void gemm_mfma_f32in_kernel(
    const float4* __restrict__ X, const u16* __restrict__ Wt,
    u16* __restrict__ Y, int nrows, int ntiles)
{
    __shared__ __align__(16) u16 Xs[64 * XS_STRIDE];
    __shared__ __align__(16) u16 Ws[128 * XS_STRIDE];
    int tid = threadIdx.x;
    stage_w(Wt, Ws, tid);
    for (int t = blockIdx.x; t < ntiles; t += gridDim.x) {
        int row0 = t * 64;
        __syncthreads();   // Ws ready / prev tile's reads done
#pragma unroll
        for (int i = 0; i < 8; ++i) {
            int idx = tid + i * 256;        // = r*32 + c4
            int r = idx >> 5, c4 = idx & 31;
            int gr = row0 + r;
            float4 v = make_float4(0.f, 0.f, 0.f, 0.f);
            if (gr < nrows) v = X[(size_t)gr * 32 + c4];
            ushort4_t o;
            o.x = f2bf(v.x); o.y = f2bf(v.y); o.z = f2bf(v.z); o.w = f2bf(v.w);
            *(ushort4_t*)&Xs[r * XS_STRIDE + c4 * 4] = o;
        }
        __syncthreads();
        gemm_core_and_store(Xs, Ws, Y, row0, nrows, tid);
    }
}

// layers 2/3: X bf16, optional fused bn(from raw stats)+relu on input, persistent
__global__ __launch_bounds__(256) void gemm_mfma_bf16in_kernel(
    const uint4* __restrict__ X, const u16* __restrict__ Wt,
    const float* __restrict__ gsum, const float* __restrict__ gsq,
    const float* __restrict__ gamma, const float* __restrict__ beta, float invN,
    u16* __restrict__ Y, int nrows, int ntiles)
{
    __shared__ __align__(16) u16 Xs[64 * XS_STRIDE];
    __shared__ __align__(16) u16 Ws[128 * XS_STRIDE];
    __shared__ float scs[D], shs[D];
    int tid = threadIdx.x;
    bool fuse = (gsum != nullptr);
    stage_w(Wt, Ws, tid);
    if (fuse && tid < D) {
        float mu = gsum[tid] * invN;
        float var = gsq[tid] * invN - mu * mu;
        float sc = gamma[tid] * rsqrtf(var + BN_EPS);
        scs[tid] = sc;
        shs[tid] = beta[tid] - mu * sc;
    }
    for (int t = blockIdx.x; t < ntiles; t += gridDim.x) {
        int row0 = t * 64;
        __syncthreads();   // Ws/scs ready / prev tile's reads done
#pragma unroll
        for (int i = 0; i < 4; ++i) {
            int idx = tid + i * 256;        // = r*16 + c8
            int r = idx >> 4, c8 = idx & 15;
            int gr = row0 + r;
            uint4 v = make_uint4(0, 0, 0, 0);
            if (gr < nrows) v = X[(size_t)gr * 16 + c8];
            if (fuse) {
                int k = c8 * 8;
                v.x = pack2bf(fmaxf(bf_lo(v.x) * scs[k]     + shs[k],     0.f),
                              fmaxf(bf_hi(v.x) * scs[k + 1] + shs[k + 1], 0.f));
                v.y = pack2bf(fmaxf(bf_lo(v.y) * scs[k + 2] + shs[k + 2], 0.f),
                              fmaxf(bf_hi(v.y) * scs[k + 3] + shs[k + 3], 0.f));
                v.z = pack2bf(fmaxf(bf_lo(v.z) * scs[k + 4] + shs[k + 4], 0.f),
                              fmaxf(bf_hi(v.z) * scs[k + 5] + shs[k + 5], 0.f));
                v.w = pack2bf(fmaxf(bf_lo(v.w) * scs[k + 6] + shs[k + 6], 0.f),
                              fmaxf(bf_hi(v.w) * scs[k + 7] + shs[k + 7], 0.f));
            }
            *(uint4*)&Xs[r * XS_STRIDE + c8 * 8] = v;
        }
        __syncthreads();
        gemm_core_and_store(Xs, Ws, Y, row0, nrows, tid);
    }
}

// ---------------- aggregation v3 (best measured: 63.6 us, VGPR 32, occ 72%) ----------------
// one wave per row; 4-deep gather batches per 16-lane group; butterfly merge.
#define ACC8(tw, duu)                                              \
    acc[0] += (duu) * bf_lo((tw).x); acc[1] += (duu) * bf_hi((tw).x); \
    acc[2] += (duu) * bf_lo((tw).y); acc[3] += (duu) * bf_hi((tw).y); \
    acc[4] += (duu) * bf_lo((tw).z); acc[5] += (duu) * bf_hi((tw).z); \
    acc[6] += (duu) * bf_lo((tw).w); acc[7] += (duu) * bf_hi((tw).w);

__global__ __launch_bounds__(256) void aggregate_kernel(
    const uint4* __restrict__ T, const int* __restrict__ colIdx,
    const int* __restrict__ rowPtr, const float* __restrict__ dinv,
    const float* __restrict__ bias, u32* __restrict__ outH, int n)
{
    int wid = threadIdx.x >> 6;
    int lane = threadIdx.x & 63;
    int row = blockIdx.x * 4 + wid;
    if (row >= n) return;
    int fg = lane & 15;
    int eg = lane >> 4;

    float dr = dinv[row];
    float acc[8] = {};

    if (eg == 0) {
        uint4 sv = T[(size_t)row * 16 + fg];
        acc[0] = dr * bf_lo(sv.x); acc[1] = dr * bf_hi(sv.x);
        acc[2] = dr * bf_lo(sv.y); acc[3] = dr * bf_hi(sv.y);
        acc[4] = dr * bf_lo(sv.z); acc[5] = dr * bf_hi(sv.z);
        acc[6] = dr * bf_lo(sv.w); acc[7] = dr * bf_hi(sv.w);
    }

    int s = rowPtr[row], e = rowPtr[row + 1];
    for (int j0 = s; j0 < e; j0 += 64) {
        int m = e - j0;
        if (m > 64) m = 64;
        int u = row;        // inactive lanes: row's own (hot) line, weight 0
        float du = 0.f;
        if (lane < m) {
            u = colIdx[j0 + lane];
            du = dinv[u];
        }
        int nc = (m + 15) >> 4;  // 16-edge sub-chunks; 4 edges per group per sub-chunk
        for (int c = 0; c < nc; ++c) {
            int b0 = c * 16 + eg;
            int u0 = __shfl(u, b0);      int u1 = __shfl(u, b0 + 4);
            int u2 = __shfl(u, b0 + 8);  int u3 = __shfl(u, b0 + 12);
            float d0 = __shfl(du, b0);      float d1 = __shfl(du, b0 + 4);
            float d2 = __shfl(du, b0 + 8);  float d3 = __shfl(du, b0 + 12);
            uint4 t0 = T[(size_t)u0 * 16 + fg];
            uint4 t1 = T[(size_t)u1 * 16 + fg];
            uint4 t2 = T[(size_t)u2 * 16 + fg];
            uint4 t3 = T[(size_t)u3 * 16 + fg];
            ACC8(t0, d0); ACC8(t1, d1); ACC8(t2, d2); ACC8(t3, d3);
        }
    }

#pragma unroll
    for (int off = 16; off < 64; off <<= 1) {
#pragma unroll
        for (int i = 0; i < 8; ++i) acc[i] += __shfl_xor(acc[i], off);
    }

    const float2* bp = (const float2*)bias;
    int pidx = fg * 4 + eg;
    float2 b = bp[pidx];
    float ox = fmaxf(dr * acc[eg * 2] + b.x, 0.f);
    float oy = fmaxf(dr * acc[eg * 2 + 1] + b.y, 0.f);
    outH[(size_t)row * 64 + pidx] = pack2bf(ox, oy);
}

// ---------------- batchnorm stats (bf16 input) ----------------
__global__ __launch_bounds__(256) void bn_stats_kernel(
    const u32* __restrict__ H, int n, float* __restrict__ gsum, float* __restrict__ gsq)
{
    int tid = threadIdx.x;
    int c = tid & 63, rr = tid >> 6;
    float sA = 0.f, sA2 = 0.f, sB = 0.f, sB2 = 0.f;
    for (int row = blockIdx.x * 4 + rr; row < n; row += gridDim.x * 4) {
        u32 v = H[(size_t)row * 64 + c];
        float a = bf_lo(v), b = bf_hi(v);
        sA += a; sA2 += a * a; sB += b; sB2 += b * b;
    }
    __shared__ float shA[256], shA2[256], shB[256], shB2[256];
    shA[tid] = sA; shA2[tid] = sA2; shB[tid] = sB; shB2[tid] = sB2;
    __syncthreads();
    if (tid < 64) {
        float tA = shA[tid] + shA[tid + 64] + shA[tid + 128] + shA[tid + 192];
        float tA2 = shA2[tid] + shA2[tid + 64] + shA2[tid + 128] + shA2[tid + 192];
        float tB = shB[tid] + shB[tid + 64] + shB[tid + 128] + shB[tid + 192];
        float tB2 = shB2[tid] + shB2[tid + 64] + shB2[tid + 128] + shB2[tid + 192];
        atomicAdd(&gsum[2 * c], tA);
        atomicAdd(&gsq[2 * c], tA2);
        atomicAdd(&gsum[2 * c + 1], tB);
        atomicAdd(&gsq[2 * c + 1], tB2);
    }
}

// ---------------- pool (bn2 from raw stats + relu) + classify + log_softmax ----------------
__global__ __launch_bounds__(256) void pool_classify_kernel(
    const u32* __restrict__ H, const float* __restrict__ gsum, const float* __restrict__ gsq,
    const float* __restrict__ gamma, const float* __restrict__ beta, float invN,
    const int* __restrict__ gstart, const float* __restrict__ fcw,
    const float* __restrict__ fcb, float* __restrict__ out)
{
    int g = blockIdx.x;
    int tid = threadIdx.x;
    int c = tid & 63, q = tid >> 6;
    float muA = gsum[2 * c] * invN, muB = gsum[2 * c + 1] * invN;
    float vA = gsq[2 * c] * invN - muA * muA, vB = gsq[2 * c + 1] * invN - muB * muB;
    float scA = gamma[2 * c] * rsqrtf(vA + BN_EPS), scB = gamma[2 * c + 1] * rsqrtf(vB + BN_EPS);
    float shA = beta[2 * c] - muA * scA, shB = beta[2 * c + 1] - muB * scB;

    int s = gstart[g], cnt = gstart[g + 1] - s;
    float aA = 0.f, aB = 0.f;
    for (int i = q; i < cnt; i += 4) {
        u32 v = H[(size_t)(s + i) * 64 + c];
        aA += fmaxf(bf_lo(v) * scA + shA, 0.f);
        aB += fmaxf(bf_hi(v) * scB + shB, 0.f);
    }
    __shared__ float sA[256], sB[256];
    __shared__ float prow[D];
    __shared__ float lg[C_CLASSES];
    sA[tid] = aA; sB[tid] = aB;
    __syncthreads();
    if (tid < 64) {
        float tA = sA[tid] + sA[tid + 64] + sA[tid + 128] + sA[tid + 192];
        float tB = sB[tid] + sB[tid + 64] + sB[tid + 128] + sB[tid + 192];
        float inv = 1.f / (float)(cnt > 1 ? cnt : 1);
        prow[2 * tid] = tA * inv;
        prow[2 * tid + 1] = tB * inv;
    }
    __syncthreads();
    if (tid < C_CLASSES) {
        float sum = fcb[tid];
        for (int d = 0; d < D; ++d) sum += prow[d] * fcw[d * C_CLASSES + tid];
        lg[tid] = sum;
    }
    __syncthreads();
    if (tid == 0) {
        float mx = -1e30f;
        for (int k = 0; k < C_CLASSES; ++k) mx = fmaxf(mx, lg[k]);
        float se = 0.f;
        for (int k = 0; k < C_CLASSES; ++k) se += expf(lg[k] - mx);
        float lse = mx + logf(se);
        for (int k = 0; k < C_CLASSES; ++k) out[(size_t)g * C_CLASSES + k] = lg[k] - lse;
    }
}

extern "C" void kernel_launch(void* const* d_in, const int* in_sizes, int n_in,
                              void* d_out, int out_size, void* d_ws, size_t ws_size,
                              hipStream_t stream) {
    const float* x   = (const float*)d_in[0];
    const int* ei    = (const int*)d_in[1];
    const int* batch = (const int*)d_in[2];
    const float* w1  = (const float*)d_in[3];
    const float* b1  = (const float*)d_in[4];
    const float* w2  = (const float*)d_in[5];
    const float* b2  = (const float*)d_in[6];
    const float* w3  = (const float*)d_in[7];
    const float* b3  = (const float*)d_in[8];
    const float* g1  = (const float*)d_in[9];
    const float* be1 = (const float*)d_in[10];
    const float* g2  = (const float*)d_in[11];
    const float* be2 = (const float*)d_in[12];
    const float* fcw = (const float*)d_in[13];
    const float* fcb = (const float*)d_in[14];

    const int N = in_sizes[0] / D;
    const int E = in_sizes[1] / 2;
    const int* src = ei;
    const int* dst = ei + E;
    const int nbuck = (N + 255) >> 8;
    const float invN = 1.f / (float)N;

    char* p = (char*)d_ws;
    auto alloc = [&](size_t bytes) -> void* {
        void* r = (void*)p;
        p += (bytes + 255) & ~(size_t)255;
        return r;
    };
    // bucketCnt + statsacc adjacent -> one memset
    int*   bucketCnt    = (int*)alloc(NBUCK_MAX * 4);
    float* statsacc     = (float*)alloc(4 * D * 4);
    float* gsum1 = statsacc, *gsq1 = statsacc + D, *gsum2 = statsacc + 2 * D, *gsq2 = statsacc + 3 * D;
    float* dinv     = (float*)alloc((size_t)N * 4);
    int*   rowPtr   = (int*)alloc((size_t)(N + 1) * 4);
    int*   colIdx   = (int*)alloc((size_t)E * 4);
    u32*   pairs    = (u32*)alloc((size_t)E * 4);
    int*   bucketBase   = (int*)alloc((NBUCK_MAX + 1) * 4);
    int*   bucketCursor = (int*)alloc(NBUCK_MAX * 4);
    int*   gstart  = (int*)alloc((G_GRAPHS + 1) * 4);
    u16*   wtAll   = (u16*)alloc((size_t)3 * D * D * 2);   // bf16 W^T x3
    u16*   tmp     = (u16*)alloc((size_t)N * D * 2);       // bf16 gemm out
    u16*   hbuf    = (u16*)alloc((size_t)N * D * 2);       // bf16 agg out

    hipMemsetAsync(bucketCnt, 0, NBUCK_MAX * 4 + 4 * D * 4, stream);

    // ---- graph structure ----
    bucket_hist_kernel<<<512, 256, 0, stream>>>(dst, bucketCnt, E, nbuck);
    scan_buckets_kernel<<<1, 512, 0, stream>>>(bucketCnt, bucketBase, bucketCursor, rowPtr, nbuck, N, E);
    scatter_pairs_kernel<<<(E + EDGE_CHUNK - 1) / EDGE_CHUNK, 256, 0, stream>>>(src, dst, bucketCursor, pairs, E);
    bucket_sort_kernel<<<nbuck, 256, 0, stream>>>(pairs, bucketBase, colIdx, rowPtr, dinv, N);
    graph_bounds_kernel<<<(N + 255) / 256, 256, 0, stream>>>(batch, gstart, N);
    wconv_kernel<<<3, 256, 0, stream>>>((const float4*)w1, (const float4*)w2, (const float4*)w3, wtAll);

    const int NT = (N + 63) / 64;            // gemm tiles
    const int GB = (NT + 1) / 2;             // exactly 2 tiles/block (even split)
    const int AB = (N + 3) / 4;              // aggregate: 4 rows per block (v3)

    gemm_mfma_f32in_kernel<<<GB, 256, 0, stream>>>((const float4*)x, wtAll, tmp, N, NT);
    aggregate_kernel<<<AB, 256, 0, stream>>>((const uint4*)tmp, colIdx, rowPtr, dinv, b1, (u32*)hbuf, N);
    gemm_mfma_bf16in_kernel<<<GB, 256, 0, stream>>>((const uint4*)hbuf, wtAll + D * D,
        nullptr, nullptr, nullptr, nullptr, 0.f, tmp, N, NT);
    aggregate_kernel<<<AB, 256, 0, stream>>>((const uint4*)tmp, colIdx, rowPtr, dinv, b2, (u32*)hbuf, N);
    bn_stats_kernel<<<256, 256, 0, stream>>>((const u32*)hbuf, N, gsum1, gsq1);
    gemm_mfma_bf16in_kernel<<<GB, 256, 0, stream>>>((const uint4*)hbuf, wtAll + 2 * D * D,
        gsum1, gsq1, g1, be1, invN, tmp, N, NT);
    aggregate_kernel<<<AB, 256, 0, stream>>>((const uint4*)tmp, colIdx, rowPtr, dinv, b3, (u32*)hbuf, N);
    bn_stats_kernel<<<256, 256, 0, stream>>>((const u32*)hbuf, N, gsum2, gsq2);
    pool_classify_kernel<<<G_GRAPHS, 256, 0, stream>>>((const u32*)hbuf, gsum2, gsq2, g2, be2, invN,
        gstart, fcw, fcb, (float*)d_out);
}